// Round 11
// baseline (241.224 us; speedup 1.0000x reference)
//
#include <hip/hip_runtime.h>
#include <hip/hip_bf16.h>

// GATConv on gfx950.
// R11: latency-chain + dependency surgery. R10: fused gemm_scatter=69us @
// VGPR=56, occ 28%, all pipes <5% -> gemm K-loop is 8 SERIALIZED feat-load->
// MFMA rounds (no regs to pipeline). Fixes: (1) hoist all 16 feat float4
// loads + bf16 cvt ahead of the MFMA chain (1 HBM latency, not 8; VGPR
// ~120 intentional -- ILP instead of never-achieved TLP); (2) prep kernel
// DELETED: bin_cur = pure count via hipMemsetAsync (graph-safe; harness
// itself memsets), reservation adds (bin<<CAPB_LOG); W converted f32->bf16
// inline in gemm (L2-hot, +~6us L2 traffic, same rounding as prep did) --
// removes prep->gemm serialization + one kernel boundary + Wb buffer.
// scatter + csr_gat byte-identical to R10 for attribution.
// Fact bank: R10: 256-bin vs 1024-bin arena differ ~4us -> write-amp at
// run~3 is minor, two-level sort has no upside. R5: random 4B global
// writes = 64B-line amplification, ~80us. R6: LDS atomics between gathers
// fence the load pipe. R2/R4/R8: hb gather is L2-miss-service-bound
// (~3TB/s, 146MB); csr_gat occupancy starvation costs 40% on it (R8->R9).

#define IN_FEATS 256
#define OUT_FEATS 128
#define NBINS 1024             // fine buckets (dst>>6); 782 used at N=50000
#define BUCK 64                // dsts per bucket
#define CAPB_LOG 12
#define CAPB (1 << CAPB_LOG)   // per-bin arena cap (mean 2046, sigma 45)
#define SORT_CAP 4096          // scatter chunk cap (E/512=3125)
#define SCAT_BLOCKS 512
#define BIN_STRIDE 16          // ints per bin cursor: 1 per 64B line

typedef __bf16 bf16x8 __attribute__((ext_vector_type(8)));
typedef float f32x4 __attribute__((ext_vector_type(4)));

// ---------- FUSED: gemm blocks [0,G) + scatter blocks [G,G+512), 256 thr ----------
__global__ __launch_bounds__(256) void gemm_scatter(
    const float* __restrict__ feat, const float* __restrict__ W,
    const float* __restrict__ attn_l, const float* __restrict__ attn_r,
    __bf16* __restrict__ hb, float* __restrict__ el, float* __restrict__ er,
    const int* __restrict__ src, const int* __restrict__ dst,
    int* __restrict__ bin_cur, unsigned* __restrict__ arena,
    int n, int E, int G) {
    __shared__ unsigned sorted[SORT_CAP];   // 16 KB bin-sorted chunk
    __shared__ int h[NBINS];                // 4 KB
    __shared__ int off[NBINS];              // 4 KB
    __shared__ int gbase[NBINS];            // 4 KB
    __shared__ int sblk[256];               // 1 KB scan buffer

    if (blockIdx.x >= G) {
        // ---------------- scatter path (counting sort, 1024 bins) ----------------
        const int t = threadIdx.x;          // 256 threads; 4 bins/thread
        const int blk = blockIdx.x - G;
        const int chunk = (E + SCAT_BLOCKS - 1) / SCAT_BLOCKS;  // 3125
        const int beg = blk * chunk;
        const int end = min(beg + chunk, E);

        h[4 * t] = 0; h[4 * t + 1] = 0; h[4 * t + 2] = 0; h[4 * t + 3] = 0;
        __syncthreads();
        for (int i = beg + t; i < end; i += 256)
            atomicAdd(&h[dst[i] >> 6], 1);             // LDS hist
        __syncthreads();

        // 4-bin/thread exclusive scan: thread totals -> 256-scan -> local prefix
        const int a0 = h[4 * t], a1 = h[4 * t + 1], a2 = h[4 * t + 2], a3 = h[4 * t + 3];
        const int tot = a0 + a1 + a2 + a3;
        sblk[t] = tot;
        __syncthreads();
        for (int o = 1; o < 256; o <<= 1) {
            int v = (t >= o) ? sblk[t - o] : 0;
            __syncthreads();
            sblk[t] += v;
            __syncthreads();
        }
        const int base = sblk[t] - tot;                // exclusive over threads
        off[4 * t] = base;
        off[4 * t + 1] = base + a0;
        off[4 * t + 2] = base + a0 + a1;
        off[4 * t + 3] = base + a0 + a1 + a2;
        // reservation: bin_cur holds pure COUNTS (memset-0); add region base
#pragma unroll
        for (int c = 0; c < 4; c++) {
            const int bin = 4 * t + c;
            const int cc = (c == 0) ? a0 : (c == 1) ? a1 : (c == 2) ? a2 : a3;
            if (cc > 0)
                gbase[bin] = (bin << CAPB_LOG) +
                             atomicAdd(&bin_cur[bin * BIN_STRIDE], cc);
        }
        h[4 * t] = 0; h[4 * t + 1] = 0; h[4 * t + 2] = 0; h[4 * t + 3] = 0;
        __syncthreads();

        for (int i = beg + t; i < end; i += 256) {     // rank + place in LDS
            int d = dst[i];
            int bin = d >> 6;
            int r = atomicAdd(&h[bin], 1);
            sorted[off[bin] + r] = ((unsigned)d << 16) | (unsigned)src[i];
        }
        __syncthreads();

        const int tot2 = end - beg;                    // contiguous run writes
        for (int j = t; j < tot2; j += 256) {
            unsigned w = sorted[j];
            int bin = w >> 22;                         // d>>6
            int pos = gbase[bin] + (j - off[bin]);
            pos = min(pos, ((bin + 1) << CAPB_LOG) - 1);
            arena[pos] = w;
        }
        return;
    }

    // ------- gemm path: 4 waves x 16 rows; feat loads hoisted; W cvt inline -------
    const int wid = threadIdx.x >> 6;
    const int lane = threadIdx.x & 63;
    const int s = lane & 15;
    const int q = lane >> 4;
    const int m0 = blockIdx.x * 64 + wid * 16;
    if (m0 >= n) return;

    const int mrow = min(m0 + s, n - 1);
    const float* arow = feat + (size_t)mrow * IN_FEATS + q * 8;

    // hoist ALL feat loads: 16 float4 issued up-front (one HBM latency)
    float4 f[16];
#pragma unroll
    for (int i = 0; i < 8; i++) {
        f[2 * i]     = *(const float4*)(arow + i * 32);
        f[2 * i + 1] = *(const float4*)(arow + i * 32 + 4);
    }
    bf16x8 av[8];
#pragma unroll
    for (int i = 0; i < 8; i++) {
        av[i][0] = (__bf16)f[2 * i].x;     av[i][1] = (__bf16)f[2 * i].y;
        av[i][2] = (__bf16)f[2 * i].z;     av[i][3] = (__bf16)f[2 * i].w;
        av[i][4] = (__bf16)f[2 * i + 1].x; av[i][5] = (__bf16)f[2 * i + 1].y;
        av[i][6] = (__bf16)f[2 * i + 1].z; av[i][7] = (__bf16)f[2 * i + 1].w;
    }

    f32x4 acc[8];
#pragma unroll
    for (int nt = 0; nt < 8; nt++) acc[nt] = (f32x4){0.f, 0.f, 0.f, 0.f};

#pragma unroll
    for (int ks = 0; ks < 8; ks++) {
        const int k0 = ks * 32;
#pragma unroll
        for (int nt = 0; nt < 8; nt++) {
            const float* wrow = W + (size_t)(nt * 16 + s) * IN_FEATS + k0 + q * 8;
            float4 b0 = *(const float4*)wrow;          // L2-hot (W=128KB)
            float4 b1 = *(const float4*)(wrow + 4);
            bf16x8 b;
            b[0] = (__bf16)b0.x; b[1] = (__bf16)b0.y;
            b[2] = (__bf16)b0.z; b[3] = (__bf16)b0.w;
            b[4] = (__bf16)b1.x; b[5] = (__bf16)b1.y;
            b[6] = (__bf16)b1.z; b[7] = (__bf16)b1.w;
            acc[nt] = __builtin_amdgcn_mfma_f32_16x16x32_bf16(av[ks], b, acc[nt], 0, 0, 0);
        }
    }

    float al[8], ar[8];
#pragma unroll
    for (int nt = 0; nt < 8; nt++) {
        al[nt] = attn_l[nt * 16 + s];
        ar[nt] = attn_r[nt * 16 + s];
    }

#pragma unroll
    for (int r = 0; r < 4; r++) {
        const int row = m0 + q * 4 + r;
        const bool ok = row < n;
        float pl = 0.f, pr = 0.f;
#pragma unroll
        for (int nt = 0; nt < 8; nt++) {
            float v = acc[nt][r];
            if (ok) hb[(size_t)row * OUT_FEATS + nt * 16 + s] = (__bf16)v;
            pl += v * al[nt];
            pr += v * ar[nt];
        }
#pragma unroll
        for (int m = 1; m < 16; m <<= 1) {
            pl += __shfl_xor(pl, m);
            pr += __shfl_xor(pr, m);
        }
        if (ok && s == 0) {
            el[row] = pl;
            er[row] = pr;
        }
    }
}

// ---- csr_gat: one block per 64-dst bin (IDENTICAL to R9/R10, count-based cin) ----
__global__ __launch_bounds__(512) void csr_gat(
    const unsigned* __restrict__ arena, const int* __restrict__ bin_cur,
    const float* __restrict__ el, const float* __restrict__ er,
    const __bf16* __restrict__ hb, float* __restrict__ out, int N) {
    __shared__ unsigned stage[CAPB];     // 16 KB dst-sorted packed edges
    __shared__ int cnt[BUCK];
    __shared__ int off[BUCK];
    __shared__ float erl[BUCK];
    const int b = blockIdx.x;
    const int t = threadIdx.x;
    const int abeg = b << CAPB_LOG;
    const int cin = min(bin_cur[b * BIN_STRIDE], CAPB);   // pure count now
    const int d0 = b * BUCK;

    if (t < BUCK) {
        cnt[t] = 0;
        erl[t] = (d0 + t < N) ? er[d0 + t] : 0.f;
    }
    __syncthreads();

    // pass 1: sub-bin histogram (coalesced arena read)
    for (int i = t; i < cin; i += 512)
        atomicAdd(&cnt[(arena[abeg + i] >> 16) & (BUCK - 1)], 1);
    __syncthreads();
    if (t < BUCK) off[t] = cnt[t];
    __syncthreads();
    for (int o = 1; o < BUCK; o <<= 1) {           // inclusive scan (64)
        int v = (t < BUCK && t >= o) ? off[t - o] : 0;
        __syncthreads();
        if (t < BUCK) off[t] += v;
        __syncthreads();
    }
    if (t < BUCK) {
        off[t] -= cnt[t];                          // exclusive offsets
        cnt[t] = 0;
    }
    __syncthreads();

    // pass 2: weight + rank into dst-sorted LDS stage (arena re-read L2-hot)
    for (int i = t; i < cin; i += 512) {
        unsigned e = arena[abeg + i];
        int d6 = (e >> 16) & (BUCK - 1);
        int u = (int)(e & 0xFFFFu);
        float x = el[u] + erl[d6];                 // el: 200KB random, L2
        x = (x > 0.f) ? x : 0.2f * x;
        float w = __expf(x);
        int r = atomicAdd(&cnt[d6], 1);            // after this, cnt[d6]==deg
        stage[off[d6] + r] = (__float_as_uint(w) & 0xFFFF0000u) | (unsigned)u;
    }
    __syncthreads();

    // gat phase: 8 waves x 8 dsts, register accumulation (proven pattern)
    const int wid = t >> 6;
    const int lane = t & 63;
    const unsigned* hbu = (const unsigned*)hb;
#pragma unroll 1
    for (int j = 0; j < BUCK / 8; j++) {
        const int d6 = wid * (BUCK / 8) + j;
        const int v = d0 + d6;
        if (v >= N) break;                         // tail bucket only
        const int rbeg = __builtin_amdgcn_readfirstlane(off[d6]);
        const int deg  = __builtin_amdgcn_readfirstlane(cnt[d6]);
        float acc0 = 0.f, acc1 = 0.f, wsum = 0.f;
        for (int c0 = rbeg; c0 < rbeg + deg; c0 += 64) {
            const int nn = min(64, rbeg + deg - c0);
            unsigned my = (lane < nn) ? stage[c0 + lane] : 0u;
            int k = 0;
            for (; k + 8 <= nn; k += 8) {
#pragma unroll
                for (int tt = 0; tt < 8; tt++) {
                    const unsigned es = (unsigned)__builtin_amdgcn_readlane((int)my, k + tt);
                    const unsigned us = es & 0xFFFFu;
                    const float ws = __uint_as_float(es & 0xFFFF0000u);
                    const unsigned pair = hbu[(size_t)us * (OUT_FEATS / 2) + lane];
                    wsum += ws;
                    acc0 += ws * __uint_as_float(pair << 16);
                    acc1 += ws * __uint_as_float(pair & 0xffff0000u);
                }
            }
            for (; k < nn; k++) {
                const unsigned es = (unsigned)__builtin_amdgcn_readlane((int)my, k);
                const unsigned us = es & 0xFFFFu;
                const float ws = __uint_as_float(es & 0xFFFF0000u);
                const unsigned pair = hbu[(size_t)us * (OUT_FEATS / 2) + lane];
                wsum += ws;
                acc0 += ws * __uint_as_float(pair << 16);
                acc1 += ws * __uint_as_float(pair & 0xffff0000u);
            }
        }
        const float dnm = fmaxf(wsum, 1e-9f);
        float2 o = make_float2(acc0 / dnm, acc1 / dnm);
        *(float2*)(out + (size_t)v * OUT_FEATS + lane * 2) = o;
    }
}

extern "C" void kernel_launch(void* const* d_in, const int* in_sizes, int n_in,
                              void* d_out, int out_size, void* d_ws, size_t ws_size,
                              hipStream_t stream) {
    const float* feat   = (const float*)d_in[0];
    const float* W      = (const float*)d_in[1];
    const float* attn_l = (const float*)d_in[2];
    const float* attn_r = (const float*)d_in[3];
    const int*   src    = (const int*)d_in[4];
    const int*   dst    = (const int*)d_in[5];
    const int N = in_sizes[0] / IN_FEATS;
    const int E = in_sizes[4];
    float* out = (float*)d_out;

    char* p = (char*)d_ws;
    auto alloc = [&](size_t bytes) -> char* {
        char* r = p;
        p += (bytes + 255) & ~(size_t)255;
        return r;
    };
    const int nbuckets = (N + BUCK - 1) / BUCK;    // 782

    __bf16* hb      = (__bf16*)alloc((size_t)N * OUT_FEATS * sizeof(__bf16));
    float*  el      = (float*)alloc((size_t)N * sizeof(float));
    float*  er      = (float*)alloc((size_t)N * sizeof(float));
    int*    bin_cur = (int*)alloc((size_t)NBINS * BIN_STRIDE * sizeof(int));
    unsigned* arena = (unsigned*)alloc((size_t)NBINS * CAPB * sizeof(unsigned));

    // bin_cur = pure per-bin counts; zero via async memset (graph-capturable)
    hipMemsetAsync(bin_cur, 0, (size_t)NBINS * BIN_STRIDE * sizeof(int), stream);

    const int G = (N + 63) / 64;                   // 782 gemm blocks
    gemm_scatter<<<dim3(G + SCAT_BLOCKS), dim3(256), 0, stream>>>(
        feat, W, attn_l, attn_r, hb, el, er, src, dst, bin_cur, arena, N, E, G);

    csr_gat<<<dim3(nbuckets), dim3(512), 0, stream>>>(arena, bin_cur, el, er,
                                                      hb, out, N);
}

// Round 13
// 218.038 us; speedup vs baseline: 1.1063x; 1.1063x over previous
//
#include <hip/hip_runtime.h>
#include <hip/hip_bf16.h>

// GATConv on gfx950.
// R13: back to the PROVEN 3-kernel pipeline (R12 coop-launch failed inside
// graph capture -> poisoned capture -> zero output; coop is off the table).
// Two attributable kernel-time cuts vs R10:
//  (1) gemm feat-load hoist, CLEAN: all 16 float4 feat loads issued before
//      the MFMA chain (one HBM latency, not 8 serialized rounds). Wb stays
//      PRE-CONVERTED by prep (R11 proved inline W-cvt in the loop = +28us;
//      the hoist itself was never measured clean).
//  (2) csr_gat split: TWO 512-thr blocks per 64-dst bin, each filters its
//      32-dst half from the bin's arena run (extra ~13MB L2-hot re-reads).
//      1564 blocks x 8 waves -> occupancy saturates. R8->R9 proved this
//      gather scales with occupancy (27%: 79us -> more waves: <73us).
// scatter + prep byte-identical to R10.
// Fact bank: R5 random 4B global writes = 64B-line write amplification.
// R6: LDS atomics between latency-critical gathers fence the load pipe.
// R2/R4/R8: hb gather is L2-miss-service-bound (~3TB/s, 146MB). R11: no
// f32->bf16 cvt inside the MFMA loop. R12: no coop launch under capture;
// ~70us of total is fixed harness overhead (sums identical across R0/R8
// at very different kernel mixes).

#define IN_FEATS 256
#define OUT_FEATS 128
#define NBINS 1024             // fine buckets (dst>>6); 782 used at N=50000
#define BUCK 64                // dsts per bucket
#define CAPB_LOG 12
#define CAPB (1 << CAPB_LOG)   // per-bin arena cap (mean 2046, sigma 45)
#define SORT_CAP 4096          // scatter chunk cap (E/512=3125)
#define SCAT_BLOCKS 512
#define BIN_STRIDE 16          // ints per bin cursor: 1 per 64B line
#define STAGE_CAP 2560         // csr_gat half-bin stage (mean 1023, +48sig)

typedef __bf16 bf16x8 __attribute__((ext_vector_type(8)));
typedef float f32x4 __attribute__((ext_vector_type(4)));

__global__ void prep(const float* __restrict__ W, __bf16* __restrict__ Wb, int nw,
                     int* __restrict__ cur) {
    int i = blockIdx.x * 256 + threadIdx.x;
    if (i < nw) Wb[i] = (__bf16)W[i];
    if (i < NBINS) cur[i * BIN_STRIDE] = i << CAPB_LOG;
}

// ---------- FUSED: gemm blocks [0,G) + scatter blocks [G,G+512), 256 thr ----------
__global__ __launch_bounds__(256) void gemm_scatter(
    const float* __restrict__ feat, const __bf16* __restrict__ Wb,
    const float* __restrict__ attn_l, const float* __restrict__ attn_r,
    __bf16* __restrict__ hb, float* __restrict__ el, float* __restrict__ er,
    const int* __restrict__ src, const int* __restrict__ dst,
    int* __restrict__ bin_cur, unsigned* __restrict__ arena,
    int n, int E, int G) {
    __shared__ unsigned sorted[SORT_CAP];   // 16 KB bin-sorted chunk
    __shared__ int h[NBINS];                // 4 KB
    __shared__ int off[NBINS];              // 4 KB
    __shared__ int gbase[NBINS];            // 4 KB
    __shared__ int sblk[256];               // 1 KB scan buffer

    if (blockIdx.x >= G) {
        // ---------------- scatter path (R10 exact) ----------------
        const int t = threadIdx.x;          // 256 threads; 4 bins/thread
        const int blk = blockIdx.x - G;
        const int chunk = (E + SCAT_BLOCKS - 1) / SCAT_BLOCKS;  // 3125
        const int beg = blk * chunk;
        const int end = min(beg + chunk, E);

        h[4 * t] = 0; h[4 * t + 1] = 0; h[4 * t + 2] = 0; h[4 * t + 3] = 0;
        __syncthreads();
        for (int i = beg + t; i < end; i += 256)
            atomicAdd(&h[dst[i] >> 6], 1);             // LDS hist
        __syncthreads();

        const int a0 = h[4 * t], a1 = h[4 * t + 1], a2 = h[4 * t + 2], a3 = h[4 * t + 3];
        const int tot = a0 + a1 + a2 + a3;
        sblk[t] = tot;
        __syncthreads();
        for (int o = 1; o < 256; o <<= 1) {
            int v = (t >= o) ? sblk[t - o] : 0;
            __syncthreads();
            sblk[t] += v;
            __syncthreads();
        }
        const int base = sblk[t] - tot;                // exclusive over threads
        off[4 * t] = base;
        off[4 * t + 1] = base + a0;
        off[4 * t + 2] = base + a0 + a1;
        off[4 * t + 3] = base + a0 + a1 + a2;
        if (a0 > 0) gbase[4 * t]     = atomicAdd(&bin_cur[(4 * t) * BIN_STRIDE], a0);
        if (a1 > 0) gbase[4 * t + 1] = atomicAdd(&bin_cur[(4 * t + 1) * BIN_STRIDE], a1);
        if (a2 > 0) gbase[4 * t + 2] = atomicAdd(&bin_cur[(4 * t + 2) * BIN_STRIDE], a2);
        if (a3 > 0) gbase[4 * t + 3] = atomicAdd(&bin_cur[(4 * t + 3) * BIN_STRIDE], a3);
        h[4 * t] = 0; h[4 * t + 1] = 0; h[4 * t + 2] = 0; h[4 * t + 3] = 0;
        __syncthreads();

        for (int i = beg + t; i < end; i += 256) {     // rank + place in LDS
            int d = dst[i];
            int bin = d >> 6;
            int r = atomicAdd(&h[bin], 1);
            sorted[off[bin] + r] = ((unsigned)d << 16) | (unsigned)src[i];
        }
        __syncthreads();

        const int tot2 = end - beg;                    // contiguous run writes
        for (int j = t; j < tot2; j += 256) {
            unsigned w = sorted[j];
            int bin = w >> 22;                         // d>>6
            int pos = gbase[bin] + (j - off[bin]);
            pos = min(pos, ((bin + 1) << CAPB_LOG) - 1);
            arena[pos] = w;
        }
        return;
    }

    // ------- gemm path: 4 waves x 16 rows; ALL feat loads hoisted (R13) -------
    const int wid = threadIdx.x >> 6;
    const int lane = threadIdx.x & 63;
    const int s = lane & 15;
    const int q = lane >> 4;
    const int m0 = blockIdx.x * 64 + wid * 16;
    if (m0 >= n) return;

    const int mrow = min(m0 + s, n - 1);
    const float* arow = feat + (size_t)mrow * IN_FEATS + q * 8;

    // hoist: 16 independent float4 loads issued back-to-back (one HBM latency)
    float4 f[16];
#pragma unroll
    for (int i = 0; i < 8; i++) {
        f[2 * i]     = *(const float4*)(arow + i * 32);
        f[2 * i + 1] = *(const float4*)(arow + i * 32 + 4);
    }
    bf16x8 av[8];
#pragma unroll
    for (int i = 0; i < 8; i++) {
        av[i][0] = (__bf16)f[2 * i].x;     av[i][1] = (__bf16)f[2 * i].y;
        av[i][2] = (__bf16)f[2 * i].z;     av[i][3] = (__bf16)f[2 * i].w;
        av[i][4] = (__bf16)f[2 * i + 1].x; av[i][5] = (__bf16)f[2 * i + 1].y;
        av[i][6] = (__bf16)f[2 * i + 1].z; av[i][7] = (__bf16)f[2 * i + 1].w;
    }

    f32x4 acc[8];
#pragma unroll
    for (int nt = 0; nt < 8; nt++) acc[nt] = (f32x4){0.f, 0.f, 0.f, 0.f};

#pragma unroll
    for (int ks = 0; ks < 8; ks++) {
        const int k0 = ks * 32;
#pragma unroll
        for (int nt = 0; nt < 8; nt++) {
            bf16x8 b = *(const bf16x8*)(Wb + (size_t)(nt * 16 + s) * IN_FEATS + k0 + q * 8);
            acc[nt] = __builtin_amdgcn_mfma_f32_16x16x32_bf16(av[ks], b, acc[nt], 0, 0, 0);
        }
    }

    float al[8], ar[8];
#pragma unroll
    for (int nt = 0; nt < 8; nt++) {
        al[nt] = attn_l[nt * 16 + s];
        ar[nt] = attn_r[nt * 16 + s];
    }

#pragma unroll
    for (int r = 0; r < 4; r++) {
        const int row = m0 + q * 4 + r;
        const bool ok = row < n;
        float pl = 0.f, pr = 0.f;
#pragma unroll
        for (int nt = 0; nt < 8; nt++) {
            float v = acc[nt][r];
            if (ok) hb[(size_t)row * OUT_FEATS + nt * 16 + s] = (__bf16)v;
            pl += v * al[nt];
            pr += v * ar[nt];
        }
#pragma unroll
        for (int m = 1; m < 16; m <<= 1) {
            pl += __shfl_xor(pl, m);
            pr += __shfl_xor(pr, m);
        }
        if (ok && s == 0) {
            el[row] = pl;
            er[row] = pr;
        }
    }
}

// ---- csr_gat: TWO blocks per bin, each owns a 32-dst half (R13) ----
__global__ __launch_bounds__(512) void csr_gat(
    const unsigned* __restrict__ arena, const int* __restrict__ bin_cur,
    const float* __restrict__ el, const float* __restrict__ er,
    const __bf16* __restrict__ hb, float* __restrict__ out, int N) {
    __shared__ unsigned stage[STAGE_CAP];  // 10 KB dst-sorted half-bin edges
    __shared__ int cnt[32];
    __shared__ int off[32];
    __shared__ float erl[32];
    const int b = blockIdx.x;
    const int bin = b >> 1;
    const int half = b & 1;
    const int t = threadIdx.x;
    const int abeg = bin << CAPB_LOG;
    const int cin = min(bin_cur[bin * BIN_STRIDE] - abeg, CAPB);
    const int d0 = bin * BUCK + half * 32;

    if (t < 32) {
        cnt[t] = 0;
        erl[t] = (d0 + t < N) ? er[d0 + t] : 0.f;
    }
    __syncthreads();

    // pass 1: filtered histogram (coalesced arena read; other half skipped)
    for (int i = t; i < cin; i += 512) {
        int d6 = (arena[abeg + i] >> 16) & (BUCK - 1);
        if ((d6 >> 5) == half) atomicAdd(&cnt[d6 & 31], 1);
    }
    __syncthreads();
    if (t < 32) off[t] = cnt[t];
    __syncthreads();
    for (int o = 1; o < 32; o <<= 1) {             // inclusive scan (32)
        int v = (t < 32 && t >= o) ? off[t - o] : 0;
        __syncthreads();
        if (t < 32) off[t] += v;
        __syncthreads();
    }
    if (t < 32) {
        off[t] -= cnt[t];                          // exclusive offsets
        cnt[t] = 0;
    }
    __syncthreads();

    // pass 2: weight + rank into dst-sorted LDS stage (arena re-read L2-hot)
    for (int i = t; i < cin; i += 512) {
        unsigned e = arena[abeg + i];
        int d6 = (e >> 16) & (BUCK - 1);
        if ((d6 >> 5) != half) continue;
        int u = (int)(e & 0xFFFFu);
        float x = el[u] + erl[d6 & 31];            // el: 200KB random, L2
        x = (x > 0.f) ? x : 0.2f * x;
        float w = __expf(x);
        int r = atomicAdd(&cnt[d6 & 31], 1);       // after this, cnt==deg
        int pos = min(off[d6 & 31] + r, STAGE_CAP - 1);  // clamp (P~0)
        stage[pos] = (__float_as_uint(w) & 0xFFFF0000u) | (unsigned)u;
    }
    __syncthreads();

    // gat phase: 8 waves x 4 dsts, register accumulation (proven pattern)
    const int wid = t >> 6;
    const int lane = t & 63;
    const unsigned* hbu = (const unsigned*)hb;
#pragma unroll 1
    for (int j = 0; j < 4; j++) {
        const int dd = wid * 4 + j;                // 0..31
        const int v = d0 + dd;
        if (v >= N) break;                         // tail only
        const int rbeg = __builtin_amdgcn_readfirstlane(off[dd]);
        const int deg  = __builtin_amdgcn_readfirstlane(cnt[dd]);
        float acc0 = 0.f, acc1 = 0.f, wsum = 0.f;
        for (int c0 = rbeg; c0 < rbeg + deg; c0 += 64) {
            const int nn = min(64, rbeg + deg - c0);
            unsigned my = (lane < nn) ? stage[min(c0 + lane, STAGE_CAP - 1)] : 0u;
            int k = 0;
            for (; k + 8 <= nn; k += 8) {
#pragma unroll
                for (int tt = 0; tt < 8; tt++) {
                    const unsigned es = (unsigned)__builtin_amdgcn_readlane((int)my, k + tt);
                    const unsigned us = es & 0xFFFFu;
                    const float ws = __uint_as_float(es & 0xFFFF0000u);
                    const unsigned pair = hbu[(size_t)us * (OUT_FEATS / 2) + lane];
                    wsum += ws;
                    acc0 += ws * __uint_as_float(pair << 16);
                    acc1 += ws * __uint_as_float(pair & 0xffff0000u);
                }
            }
            for (; k < nn; k++) {
                const unsigned es = (unsigned)__builtin_amdgcn_readlane((int)my, k);
                const unsigned us = es & 0xFFFFu;
                const float ws = __uint_as_float(es & 0xFFFF0000u);
                const unsigned pair = hbu[(size_t)us * (OUT_FEATS / 2) + lane];
                wsum += ws;
                acc0 += ws * __uint_as_float(pair << 16);
                acc1 += ws * __uint_as_float(pair & 0xffff0000u);
            }
        }
        const float dnm = fmaxf(wsum, 1e-9f);
        float2 o = make_float2(acc0 / dnm, acc1 / dnm);
        *(float2*)(out + (size_t)v * OUT_FEATS + lane * 2) = o;
    }
}

extern "C" void kernel_launch(void* const* d_in, const int* in_sizes, int n_in,
                              void* d_out, int out_size, void* d_ws, size_t ws_size,
                              hipStream_t stream) {
    const float* feat   = (const float*)d_in[0];
    const float* W      = (const float*)d_in[1];
    const float* attn_l = (const float*)d_in[2];
    const float* attn_r = (const float*)d_in[3];
    const int*   src    = (const int*)d_in[4];
    const int*   dst    = (const int*)d_in[5];
    const int N = in_sizes[0] / IN_FEATS;
    const int E = in_sizes[4];
    float* out = (float*)d_out;

    char* p = (char*)d_ws;
    auto alloc = [&](size_t bytes) -> char* {
        char* r = p;
        p += (bytes + 255) & ~(size_t)255;
        return r;
    };
    const int nbuckets = (N + BUCK - 1) / BUCK;    // 782

    __bf16* hb      = (__bf16*)alloc((size_t)N * OUT_FEATS * sizeof(__bf16));
    __bf16* Wb      = (__bf16*)alloc((size_t)OUT_FEATS * IN_FEATS * sizeof(__bf16));
    float*  el      = (float*)alloc((size_t)N * sizeof(float));
    float*  er      = (float*)alloc((size_t)N * sizeof(float));
    int*    bin_cur = (int*)alloc((size_t)NBINS * BIN_STRIDE * sizeof(int));
    unsigned* arena = (unsigned*)alloc((size_t)NBINS * CAPB * sizeof(unsigned));

    const int nw = OUT_FEATS * IN_FEATS;           // 32768 (covers NBINS init)
    prep<<<dim3((nw + 255) / 256), dim3(256), 0, stream>>>(W, Wb, nw, bin_cur);

    const int G = (N + 63) / 64;                   // 782 gemm blocks
    gemm_scatter<<<dim3(G + SCAT_BLOCKS), dim3(256), 0, stream>>>(
        feat, Wb, attn_l, attn_r, hb, el, er, src, dst, bin_cur, arena, N, E, G);

    csr_gat<<<dim3(2 * nbuckets), dim3(512), 0, stream>>>(arena, bin_cur, el, er,
                                                          hb, out, N);
}